// Round 3
// baseline (1573.530 us; speedup 1.0000x reference)
//
#include <hip/hip_runtime.h>
#include <math.h>

static constexpr int S_LEN  = 2048;
static constexpr int NHEADS = 16;
static constexpr int DHEAD  = 64;
static constexpr int DMODEL = 1024;

// ---------- swizzled LDS float4 tile helpers ----------
template<int W>
__device__ __forceinline__ float4 ld4s(const float* buf, int row, int cq) {
  int p = (cq ^ (row >> 2)) & (W / 4 - 1);
  return *reinterpret_cast<const float4*>(buf + row * W + (p << 2));
}
template<int W>
__device__ __forceinline__ void st4s(float* buf, int row, int cq, float4 v) {
  int p = (cq ^ (row >> 2)) & (W / 4 - 1);
  *reinterpret_cast<float4*>(buf + row * W + (p << 2)) = v;
}

// ---------- hyperbolic map scalar factors ----------
__device__ __forceinline__ void expmap_factor(float nsq, float& f, float& rn2) {
  float norm   = sqrtf(nsq + 1e-8f);
  float target = fminf(tanhf(norm), 0.9f);
  float fr     = target / norm;
  float r2     = fr * fr * nsq;
  float rn     = sqrtf(r2 + 1e-8f);
  const float maxn = 1.0f - 1e-5f;
  if (rn > maxn) { fr *= maxn / rn; r2 = fr * fr * nsq; }
  f = fr; rn2 = r2;
}
__device__ __forceinline__ float logmap_factor(float nsq) {
  float norm = sqrtf(nsq + 1e-8f);
  float nc   = fminf(norm, 1.0f - 1e-5f);
  float arg  = fminf(nc, 0.99f);
  return atanhf(arg) / nc;
}

// ---------- fused GEMM: C = X @ Wt^T + bias, per-head map epilogue ----------
// VAR 0/1: Q/K -> exp_map, write [b,h,s,d]
// VAR 2:   V   -> log_map(exp_map(.)), write [b,h,s,d]
// VAR 3:   plain, write [m,n] full-width (final output GEMM)
template<int VAR>
__global__ __launch_bounds__(256)
void gemm_fused(const float* __restrict__ X, const float* __restrict__ Wt,
                const float* __restrict__ bias, float* __restrict__ out)
{
  __shared__ float Xs[64 * 32];
  __shared__ float Wsh[64 * 32];
  __shared__ float Cs[64 * 64];
  __shared__ float part[64 * 4];
  __shared__ float facs[64];

  const int t  = threadIdx.x;
  const int m0 = blockIdx.x * 64;
  const int n0 = blockIdx.y * 64;
  const int ti = t & 15, tj = t >> 4;

  float acc[4][4];
  #pragma unroll
  for (int r = 0; r < 4; ++r)
    #pragma unroll
    for (int c = 0; c < 4; ++c) acc[r][c] = 0.0f;

  for (int k0 = 0; k0 < DMODEL; k0 += 32) {
    __syncthreads();
    #pragma unroll
    for (int i = 0; i < 2; ++i) {
      int cid = t + 256 * i;
      int row = cid >> 3, cq = cid & 7;
      float4 xv = *reinterpret_cast<const float4*>(X + (size_t)(m0 + row) * DMODEL + k0 + (cq << 2));
      st4s<32>(Xs, row, cq, xv);
      float4 wv = *reinterpret_cast<const float4*>(Wt + (size_t)(n0 + row) * DMODEL + k0 + (cq << 2));
      st4s<32>(Wsh, row, cq, wv);
    }
    __syncthreads();
    #pragma unroll
    for (int kq = 0; kq < 8; ++kq) {
      float4 a[4], bb[4];
      #pragma unroll
      for (int r = 0; r < 4; ++r) a[r] = ld4s<32>(Xs, 4 * ti + r, kq);
      #pragma unroll
      for (int c = 0; c < 4; ++c) bb[c] = ld4s<32>(Wsh, 4 * tj + c, kq);
      #pragma unroll
      for (int r = 0; r < 4; ++r)
        #pragma unroll
        for (int c = 0; c < 4; ++c) {
          acc[r][c] = fmaf(a[r].x, bb[c].x, acc[r][c]);
          acc[r][c] = fmaf(a[r].y, bb[c].y, acc[r][c]);
          acc[r][c] = fmaf(a[r].z, bb[c].z, acc[r][c]);
          acc[r][c] = fmaf(a[r].w, bb[c].w, acc[r][c]);
        }
    }
  }

  {
    float4 bv = *reinterpret_cast<const float4*>(bias + n0 + 4 * tj);
    #pragma unroll
    for (int r = 0; r < 4; ++r) {
      acc[r][0] += bv.x; acc[r][1] += bv.y; acc[r][2] += bv.z; acc[r][3] += bv.w;
    }
  }

  #pragma unroll
  for (int r = 0; r < 4; ++r)
    st4s<64>(Cs, 4 * ti + r, tj, make_float4(acc[r][0], acc[r][1], acc[r][2], acc[r][3]));
  __syncthreads();

  if (VAR == 3) {
    const int row = t >> 2, prt = t & 3;
    const size_t gbase = (size_t)(m0 + row) * DMODEL + n0;
    #pragma unroll
    for (int i = 0; i < 4; ++i) {
      int cq = 4 * prt + i;
      float4 v = ld4s<64>(Cs, row, cq);
      *reinterpret_cast<float4*>(out + gbase + (cq << 2)) = v;
    }
    return;
  }

  {
    const int row = t >> 2, prt = t & 3;
    float ss = 0.0f;
    #pragma unroll
    for (int i = 0; i < 4; ++i) {
      int cq = 4 * prt + i;
      float4 v = ld4s<64>(Cs, row, cq);
      ss += v.x * v.x + v.y * v.y + v.z * v.z + v.w * v.w;
    }
    part[row * 4 + prt] = ss;
  }
  __syncthreads();
  if (t < 64) {
    float nsq = part[t * 4 + 0] + part[t * 4 + 1] + part[t * 4 + 2] + part[t * 4 + 3];
    float f, rn2;
    expmap_factor(nsq, f, rn2);
    if (VAR == 2) f *= logmap_factor(rn2);
    facs[t] = f;
  }
  __syncthreads();
  {
    const int row = t >> 2, prt = t & 3;
    const int m = m0 + row;
    const int b = m >> 11, sr = m & (S_LEN - 1), h = n0 >> 6;
    const float f = facs[row];
    float* obase = out + (((size_t)(b * NHEADS + h)) * S_LEN + sr) * DHEAD;
    #pragma unroll
    for (int i = 0; i < 4; ++i) {
      int cq = 4 * prt + i;
      float4 v = ld4s<64>(Cs, row, cq);
      v.x *= f; v.y *= f; v.z *= f; v.w *= f;
      *reinterpret_cast<float4*>(obase + (cq << 2)) = v;
    }
  }
}

// ---------- flash-style hyperbolic attention ----------
// Q tile 32 rows, KV tile 64 rows, 256 threads: ti(16)x2 rows, tj(16)x4 cols.
// Scores bounded in [-0.458, 0] => no online max needed; e = exp(score).
// exp(-0.25*atanh(n)) == ((1-n)/(1+n))^{1/8}.
// ||q_hyp||^2 / ||k_hyp||^2 computed on the fly from staged LDS tiles
// (no global q2/k2 buffers -> ws usage fits exactly in 4*NTOK floats).
__global__ __launch_bounds__(256)
void attn_kernel(const float* __restrict__ Qh, const float* __restrict__ Kh,
                 const float* __restrict__ Vt, float* __restrict__ Om)
{
  __shared__ float Qt[32 * 64];
  __shared__ float Kt[64 * 64];
  __shared__ float Vs[64 * 64];
  __shared__ float Et[32 * 64];
  __shared__ float red[32 * 16];
  __shared__ float q2s[32];
  __shared__ float k2s[64];
  __shared__ float dens[32];
  __shared__ float facs[32];

  const int t  = threadIdx.x;
  const int ti = t & 15, tj = t >> 4;
  const int q0 = blockIdx.x * 32;
  const int h = blockIdx.y, b = blockIdx.z;
  const size_t bh = (size_t)b * NHEADS + h;
  const float* Qbase = Qh + (bh * S_LEN + q0) * DHEAD;
  const float* Kbase = Kh + bh * S_LEN * DHEAD;
  const float* Vbase = Vt + bh * S_LEN * DHEAD;

  #pragma unroll
  for (int i = 0; i < 2; ++i) {
    int cid = t + 256 * i;
    int row = cid >> 4, cq = cid & 15;
    float4 v = *reinterpret_cast<const float4*>(Qbase + row * DHEAD + (cq << 2));
    st4s<64>(Qt, row, cq, v);
  }
  __syncthreads();

  // q-norms: 32 rows, 8 threads/row, 8 elems (2 chunks) each
  {
    int row = t >> 3, oct = t & 7;
    float4 a = ld4s<64>(Qt, row, 2 * oct);
    float4 c = ld4s<64>(Qt, row, 2 * oct + 1);
    red[row * 8 + oct] = a.x * a.x + a.y * a.y + a.z * a.z + a.w * a.w
                       + c.x * c.x + c.y * c.y + c.z * c.z + c.w * c.w;
  }
  __syncthreads();
  if (t < 32) {
    float s = 0.0f;
    #pragma unroll
    for (int j = 0; j < 8; ++j) s += red[t * 8 + j];
    q2s[t] = s;
  }
  __syncthreads();

  float x2r[2], Bir[2];
  #pragma unroll
  for (int r = 0; r < 2; ++r) { x2r[r] = q2s[2 * ti + r]; Bir[r] = 1.0f - x2r[r]; }

  float o[2][4];
  float den_p[2] = {0.0f, 0.0f};
  #pragma unroll
  for (int r = 0; r < 2; ++r)
    #pragma unroll
    for (int c = 0; c < 4; ++c) o[r][c] = 0.0f;

  for (int kt = 0; kt < S_LEN / 64; ++kt) {
    __syncthreads();
    const float* Kb = Kbase + (size_t)kt * 64 * DHEAD;
    const float* Vb = Vbase + (size_t)kt * 64 * DHEAD;
    #pragma unroll
    for (int i = 0; i < 4; ++i) {
      int cid = t + 256 * i;
      int row = cid >> 4, cq = cid & 15;
      st4s<64>(Kt, row, cq, *reinterpret_cast<const float4*>(Kb + row * DHEAD + (cq << 2)));
      st4s<64>(Vs, row, cq, *reinterpret_cast<const float4*>(Vb + row * DHEAD + (cq << 2)));
    }
    __syncthreads();

    // k-norms: 64 rows, 4 threads/row, 16 elems (4 chunks) each
    {
      int row = t >> 2, prt = t & 3;
      float ss = 0.0f;
      #pragma unroll
      for (int i = 0; i < 4; ++i) {
        float4 v = ld4s<64>(Kt, row, 4 * prt + i);
        ss += v.x * v.x + v.y * v.y + v.z * v.z + v.w * v.w;
      }
      red[row * 4 + prt] = ss;
    }
    __syncthreads();
    if (t < 64) k2s[t] = red[t * 4 + 0] + red[t * 4 + 1] + red[t * 4 + 2] + red[t * 4 + 3];
    __syncthreads();

    // S = Q . K^T
    float s[2][4];
    #pragma unroll
    for (int r = 0; r < 2; ++r)
      #pragma unroll
      for (int c = 0; c < 4; ++c) s[r][c] = 0.0f;
    #pragma unroll
    for (int kq = 0; kq < 16; ++kq) {
      float4 a[2], bb[4];
      #pragma unroll
      for (int r = 0; r < 2; ++r) a[r] = ld4s<64>(Qt, 2 * ti + r, kq);
      #pragma unroll
      for (int c = 0; c < 4; ++c) bb[c] = ld4s<64>(Kt, 4 * tj + c, kq);
      #pragma unroll
      for (int r = 0; r < 2; ++r)
        #pragma unroll
        for (int c = 0; c < 4; ++c) {
          s[r][c] = fmaf(a[r].x, bb[c].x, s[r][c]);
          s[r][c] = fmaf(a[r].y, bb[c].y, s[r][c]);
          s[r][c] = fmaf(a[r].z, bb[c].z, s[r][c]);
          s[r][c] = fmaf(a[r].w, bb[c].w, s[r][c]);
        }
    }

    float y2c[4], Cjc[4];
    #pragma unroll
    for (int c = 0; c < 4; ++c) { y2c[c] = k2s[4 * tj + c]; Cjc[c] = 1.0f + y2c[c]; }

    // score transform: e = ((1-nn)/(1+nn))^(1/8)  [== exp(-0.25*atanh(nn))]
    #pragma unroll
    for (int r = 0; r < 2; ++r) {
      float e[4];
      #pragma unroll
      for (int c = 0; c < 4; ++c) {
        float xy  = s[r][c];
        float t2  = xy + xy;
        float A   = Cjc[c] + t2;
        float d0  = fmaf(x2r[r], y2c[c], 1.0f) - t2;
        float den = fmaxf(d0, 1e-10f);
        float u   = A * x2r[r];
        float vv  = Bir[r] * xy;
        float pp  = fmaf(-2.0f, vv, u);
        float num = fmaf(A, pp, Bir[r] * Bir[r] * y2c[c]);
        float mm  = fmaxf(num, 0.0f) / (den * den);
        float nn  = fminf(sqrtf(mm + 1e-8f), 0.95f);
        float ratio = (1.0f - nn) / (1.0f + nn);
        e[c] = sqrtf(sqrtf(sqrtf(ratio)));
      }
      den_p[r] += e[0] + e[1] + e[2] + e[3];
      st4s<64>(Et, 2 * ti + r, tj, make_float4(e[0], e[1], e[2], e[3]));
    }
    __syncthreads();

    // PV: o += E . V
    #pragma unroll
    for (int jq = 0; jq < 16; ++jq) {
      float4 e_[2];
      #pragma unroll
      for (int r = 0; r < 2; ++r) e_[r] = ld4s<64>(Et, 2 * ti + r, jq);
      float4 v_[4];
      #pragma unroll
      for (int jj = 0; jj < 4; ++jj) v_[jj] = ld4s<64>(Vs, 4 * jq + jj, tj);
      #pragma unroll
      for (int r = 0; r < 2; ++r) {
        float4 e = e_[r];
        o[r][0] = fmaf(e.x, v_[0].x, o[r][0]);
        o[r][0] = fmaf(e.y, v_[1].x, o[r][0]);
        o[r][0] = fmaf(e.z, v_[2].x, o[r][0]);
        o[r][0] = fmaf(e.w, v_[3].x, o[r][0]);
        o[r][1] = fmaf(e.x, v_[0].y, o[r][1]);
        o[r][1] = fmaf(e.y, v_[1].y, o[r][1]);
        o[r][1] = fmaf(e.z, v_[2].y, o[r][1]);
        o[r][1] = fmaf(e.w, v_[3].y, o[r][1]);
        o[r][2] = fmaf(e.x, v_[0].z, o[r][2]);
        o[r][2] = fmaf(e.y, v_[1].z, o[r][2]);
        o[r][2] = fmaf(e.z, v_[2].z, o[r][2]);
        o[r][2] = fmaf(e.w, v_[3].z, o[r][2]);
        o[r][3] = fmaf(e.x, v_[0].w, o[r][3]);
        o[r][3] = fmaf(e.y, v_[1].w, o[r][3]);
        o[r][3] = fmaf(e.z, v_[2].w, o[r][3]);
        o[r][3] = fmaf(e.w, v_[3].w, o[r][3]);
      }
    }
  }

  // denominator reduce across the 16 tj groups
  #pragma unroll
  for (int r = 0; r < 2; ++r) red[(2 * ti + r) * 16 + tj] = den_p[r];
  __syncthreads();
  if (t < 32) {
    float d = 0.0f;
    #pragma unroll
    for (int j = 0; j < 16; ++j) d += red[t * 16 + j];
    dens[t] = 1.0f / d;
  }
  __syncthreads();

  float np_[2];
  #pragma unroll
  for (int r = 0; r < 2; ++r) {
    float rd = dens[2 * ti + r];
    o[r][0] *= rd; o[r][1] *= rd; o[r][2] *= rd; o[r][3] *= rd;
    np_[r] = o[r][0] * o[r][0] + o[r][1] * o[r][1] + o[r][2] * o[r][2] + o[r][3] * o[r][3];
  }
  #pragma unroll
  for (int r = 0; r < 2; ++r) red[(2 * ti + r) * 16 + tj] = np_[r];
  __syncthreads();
  if (t < 32) {
    float nsq = 0.0f;
    #pragma unroll
    for (int j = 0; j < 16; ++j) nsq += red[t * 16 + j];
    float f, rn2;
    expmap_factor(nsq, f, rn2);
    facs[t] = f * logmap_factor(rn2);
  }
  __syncthreads();
  {
    #pragma unroll
    for (int r = 0; r < 2; ++r) {
      float f = facs[2 * ti + r];
      float4 v = make_float4(o[r][0] * f, o[r][1] * f, o[r][2] * f, o[r][3] * f);
      size_t addr = ((size_t)b * S_LEN + (q0 + 2 * ti + r)) * DMODEL + h * DHEAD + 4 * tj;
      *reinterpret_cast<float4*>(Om + addr) = v;
    }
  }
}

extern "C" void kernel_launch(void* const* d_in, const int* in_sizes, int n_in,
                              void* d_out, int out_size, void* d_ws, size_t ws_size,
                              hipStream_t stream) {
  const float* H  = (const float*)d_in[0];
  const float* Wq = (const float*)d_in[1];
  const float* bq = (const float*)d_in[2];
  const float* Wk = (const float*)d_in[3];
  const float* bk = (const float*)d_in[4];
  const float* Wv = (const float*)d_in[5];
  const float* bv = (const float*)d_in[6];
  const float* Wo = (const float*)d_in[7];
  const float* bo = (const float*)d_in[8];

  float* ws = (float*)d_ws;
  const size_t NTOK = (size_t)2 * S_LEN * DMODEL;   // 4,194,304 floats
  float* Qh = ws;                                   // total ws use: 4*NTOK f32 = 64 MiB
  float* Kh = Qh + NTOK;
  float* Vt = Kh + NTOK;
  float* Om = Vt + NTOK;

  dim3 gg(64, 16), gb(256);
  gemm_fused<0><<<gg, gb, 0, stream>>>(H, Wq, bq, Qh);
  gemm_fused<1><<<gg, gb, 0, stream>>>(H, Wk, bk, Kh);
  gemm_fused<2><<<gg, gb, 0, stream>>>(H, Wv, bv, Vt);
  attn_kernel<<<dim3(S_LEN / 32, NHEADS, 2), 256, 0, stream>>>(Qh, Kh, Vt, Om);
  gemm_fused<3><<<gg, gb, 0, stream>>>(Om, Wo, bo, (float*)d_out);
}

// Round 4
// 516.556 us; speedup vs baseline: 3.0462x; 3.0462x over previous
//
#include <hip/hip_runtime.h>
#include <math.h>

// R4: full bf16-MFMA rewrite.
//  - conv H,W -> bf16 once; GEMMs 128x64 tile BK=64, 4 waves (2x2), mfma 16x16x32 bf16
//  - Q/K ws [b,h,s,d] bf16; V ws [b,h,d,s] bf16 (transposed in V-GEMM epilogue via padded LDS)
//  - attn: 64 q-rows/block, 4 waves x 16 rows; KV tile 64; QK->transform(f32)->E via
//    per-wave LDS->PV, all MFMA; norms on the fly from bf16 operands (consistency);
//    no online max needed (scores in [-0.458,0]); XCD-swizzled grid.
// Convention: D = A * staged^T, both operands read as row-major K-contig frags:
//   frag lane l: row = l&15, k = (l>>4)*8 + j;  D: col = l&15, row = 4*(l>>4)+reg.

typedef short bf16x8 __attribute__((ext_vector_type(8)));
typedef float f32x4 __attribute__((ext_vector_type(4)));

static constexpr int S_LEN = 2048;
static constexpr int NH = 16;
static constexpr int DM = 1024;

__device__ __forceinline__ unsigned short f2b(float x) {
  unsigned u = __builtin_bit_cast(unsigned, x);
  return (unsigned short)((u + 0x7FFFu + ((u >> 16) & 1u)) >> 16);
}
__device__ __forceinline__ float b2f(unsigned short h) {
  unsigned u = ((unsigned)h) << 16;
  return __builtin_bit_cast(float, u);
}
__device__ __forceinline__ float frcp(float x) {
  float r; asm("v_rcp_f32 %0, %1" : "=v"(r) : "v"(x)); return r;
}
__device__ __forceinline__ bf16x8 ldfrag(const void* p) {
  return __builtin_bit_cast(bf16x8, *(const uint4*)p);
}
__device__ __forceinline__ float sumsq8(bf16x8 v) {
  float s = 0.f;
  #pragma unroll
  for (int j = 0; j < 8; ++j) { float f = b2f((unsigned short)v[j]); s = fmaf(f, f, s); }
  return s;
}
__device__ __forceinline__ void expmap_factor(float nsq, float& f, float& rn2) {
  float norm   = sqrtf(nsq + 1e-8f);
  float target = fminf(tanhf(norm), 0.9f);
  float fr     = target / norm;
  float r2     = fr * fr * nsq;
  float rn     = sqrtf(r2 + 1e-8f);
  const float maxn = 1.0f - 1e-5f;
  if (rn > maxn) { fr *= maxn / rn; r2 = fr * fr * nsq; }
  f = fr; rn2 = r2;
}
__device__ __forceinline__ float logmap_factor(float nsq) {
  float norm = sqrtf(nsq + 1e-8f);
  float nc   = fminf(norm, 1.0f - 1e-5f);
  float arg  = fminf(nc, 0.99f);
  return atanhf(arg) / nc;
}

// ---------------- converters ----------------
__global__ __launch_bounds__(256)
void conv_f2b(const float* __restrict__ src, uint4* __restrict__ dst) {
  int i = blockIdx.x * 256 + threadIdx.x;
  const float4* s4 = (const float4*)src;
  float4 a = s4[2 * i], b = s4[2 * i + 1];
  uint4 o;
  o.x = (unsigned)f2b(a.x) | ((unsigned)f2b(a.y) << 16);
  o.y = (unsigned)f2b(a.z) | ((unsigned)f2b(a.w) << 16);
  o.z = (unsigned)f2b(b.x) | ((unsigned)f2b(b.y) << 16);
  o.w = (unsigned)f2b(b.z) | ((unsigned)f2b(b.w) << 16);
  dst[i] = o;
}
__global__ __launch_bounds__(256)
void conv_w4(const float* __restrict__ w0, const float* __restrict__ w1,
             const float* __restrict__ w2, const float* __restrict__ w3,
             uint4* __restrict__ d0, uint4* __restrict__ d1,
             uint4* __restrict__ d2, uint4* __restrict__ d3) {
  const float* s = blockIdx.y == 0 ? w0 : blockIdx.y == 1 ? w1 : blockIdx.y == 2 ? w2 : w3;
  uint4* d = blockIdx.y == 0 ? d0 : blockIdx.y == 1 ? d1 : blockIdx.y == 2 ? d2 : d3;
  int i = blockIdx.x * 256 + threadIdx.x;
  const float4* s4 = (const float4*)s;
  float4 a = s4[2 * i], b = s4[2 * i + 1];
  uint4 o;
  o.x = (unsigned)f2b(a.x) | ((unsigned)f2b(a.y) << 16);
  o.y = (unsigned)f2b(a.z) | ((unsigned)f2b(a.w) << 16);
  o.z = (unsigned)f2b(b.x) | ((unsigned)f2b(b.y) << 16);
  o.w = (unsigned)f2b(b.z) | ((unsigned)f2b(b.w) << 16);
  d[i] = o;
}

// ---------------- GEMM: out = Xb @ Wb^T + bias, epilogue per VAR ----------------
// VAR 0/1: Q/K -> exp_map -> bf16 [b,h,s,d].  VAR 2: V -> log(exp(.)) -> bf16 [b,h,d,s].
// VAR 3: plain f32 [m][1024] (final output).
// Tile: BM=128, BN=64(=1 head), BK=64. 4 waves (wr 0..1 x wc 0..1), wave tile 64x32.
template<int VAR>
__global__ __launch_bounds__(256)
void gemm_mfma(const unsigned short* __restrict__ Xb, const unsigned short* __restrict__ Wb,
               const float* __restrict__ bias, void* __restrict__ outp)
{
  __shared__ char smem[25600];
  char* Xs = smem;              // [128][64] bf16, 16KB, XOR-swizzled 16B chunks
  char* Ws = smem + 16384;      // [64][64]  bf16, 8KB
  float* nsq = (float*)(smem + 24576);  // [2][128]
  const int t = threadIdx.x, wid = t >> 6, lane = t & 63;
  const int wr = wid >> 1, wc = wid & 1;
  const int g = lane >> 4, c = lane & 15;
  const int m0 = blockIdx.x * 128, n0 = blockIdx.y * 64;

  f32x4 acc[4][2];
  #pragma unroll
  for (int i = 0; i < 4; ++i)
    #pragma unroll
    for (int j = 0; j < 2; ++j) acc[i][j] = (f32x4){0.f, 0.f, 0.f, 0.f};

  #pragma unroll 1
  for (int k0 = 0; k0 < DM; k0 += 64) {
    __syncthreads();
    #pragma unroll
    for (int i = 0; i < 4; ++i) {
      int id = t + 256 * i, row = id >> 3, ch = id & 7;
      uint4 v = *(const uint4*)(Xb + (size_t)(m0 + row) * DM + k0 + 8 * ch);
      *(uint4*)(Xs + row * 128 + ((16 * ch) ^ (16 * (row & 7)))) = v;
    }
    #pragma unroll
    for (int i = 0; i < 2; ++i) {
      int id = t + 256 * i, row = id >> 3, ch = id & 7;
      uint4 v = *(const uint4*)(Wb + (size_t)(n0 + row) * DM + k0 + 8 * ch);
      *(uint4*)(Ws + row * 128 + ((16 * ch) ^ (16 * (row & 7)))) = v;
    }
    __syncthreads();
    bf16x8 af[4][2], bfr[2][2];
    #pragma unroll
    for (int mt = 0; mt < 4; ++mt) {
      int row = 64 * wr + 16 * mt + c, sw = 16 * (row & 7);
      af[mt][0] = ldfrag(Xs + row * 128 + ((16 * g) ^ sw));
      af[mt][1] = ldfrag(Xs + row * 128 + ((64 + 16 * g) ^ sw));
    }
    #pragma unroll
    for (int nt = 0; nt < 2; ++nt) {
      int row = 32 * wc + 16 * nt + c, sw = 16 * (row & 7);
      bfr[nt][0] = ldfrag(Ws + row * 128 + ((16 * g) ^ sw));
      bfr[nt][1] = ldfrag(Ws + row * 128 + ((64 + 16 * g) ^ sw));
    }
    #pragma unroll
    for (int mt = 0; mt < 4; ++mt)
      #pragma unroll
      for (int nt = 0; nt < 2; ++nt) {
        acc[mt][nt] = __builtin_amdgcn_mfma_f32_16x16x32_bf16(af[mt][0], bfr[nt][0], acc[mt][nt], 0, 0, 0);
        acc[mt][nt] = __builtin_amdgcn_mfma_f32_16x16x32_bf16(af[mt][1], bfr[nt][1], acc[mt][nt], 0, 0, 0);
      }
  }

  float bv[2];
  #pragma unroll
  for (int nt = 0; nt < 2; ++nt) bv[nt] = bias[n0 + 32 * wc + 16 * nt + c];
  #pragma unroll
  for (int mt = 0; mt < 4; ++mt)
    #pragma unroll
    for (int nt = 0; nt < 2; ++nt)
      #pragma unroll
      for (int r = 0; r < 4; ++r) acc[mt][nt][r] += bv[nt];

  if constexpr (VAR == 3) {
    float* out = (float*)outp;
    #pragma unroll
    for (int mt = 0; mt < 4; ++mt)
      #pragma unroll
      for (int nt = 0; nt < 2; ++nt)
        #pragma unroll
        for (int r = 0; r < 4; ++r) {
          int m = m0 + 64 * wr + 16 * mt + 4 * g + r;
          out[(size_t)m * DM + n0 + 32 * wc + 16 * nt + c] = acc[mt][nt][r];
        }
    return;
  } else {
    // row ||.||^2: intra-wave over 32 cols, cross-wave (wc pair) via LDS
    float p[4][4];
    #pragma unroll
    for (int mt = 0; mt < 4; ++mt)
      #pragma unroll
      for (int r = 0; r < 4; ++r) {
        float v = acc[mt][0][r] * acc[mt][0][r] + acc[mt][1][r] * acc[mt][1][r];
        v += __shfl_xor(v, 1); v += __shfl_xor(v, 2); v += __shfl_xor(v, 4); v += __shfl_xor(v, 8);
        p[mt][r] = v;
      }
    __syncthreads();
    if (c == 0) {
      #pragma unroll
      for (int mt = 0; mt < 4; ++mt)
        #pragma unroll
        for (int r = 0; r < 4; ++r)
          nsq[wc * 128 + 64 * wr + 16 * mt + 4 * g + r] = p[mt][r];
    }
    __syncthreads();
    float fac[4][4];
    #pragma unroll
    for (int mt = 0; mt < 4; ++mt)
      #pragma unroll
      for (int r = 0; r < 4; ++r) {
        int row = 64 * wr + 16 * mt + 4 * g + r;
        float v = nsq[row] + nsq[128 + row];
        float f, rn2; expmap_factor(v, f, rn2);
        if (VAR == 2) f *= logmap_factor(rn2);
        fac[mt][r] = f;
      }
    const int h = (int)blockIdx.y;   // BN=64 == one head
    if constexpr (VAR != 2) {
      unsigned short* out = (unsigned short*)outp;
      #pragma unroll
      for (int mt = 0; mt < 4; ++mt)
        #pragma unroll
        for (int nt = 0; nt < 2; ++nt)
          #pragma unroll
          for (int r = 0; r < 4; ++r) {
            int m = m0 + 64 * wr + 16 * mt + 4 * g + r;
            int b = m >> 11, s = m & (S_LEN - 1);
            int d = 32 * wc + 16 * nt + c;
            out[((size_t)(b * NH + h) * S_LEN + s) * 64 + d] = f2b(acc[mt][nt][r] * fac[mt][r]);
          }
    } else {
      // transpose via padded LDS [32 d][72 bf16], per-wave region (overlaps Xs/Ws: synced above)
      char* tb = smem + wid * 4608;
      #pragma unroll
      for (int mt = 0; mt < 4; ++mt)
        #pragma unroll
        for (int nt = 0; nt < 2; ++nt)
          #pragma unroll
          for (int r = 0; r < 4; ++r) {
            int d = 16 * nt + c, sl = 16 * mt + 4 * g + r;
            *(unsigned short*)(tb + 144 * d + 2 * sl) = f2b(acc[mt][nt][r] * fac[mt][r]);
          }
      asm volatile("s_waitcnt lgkmcnt(0)" ::: "memory");
      unsigned short* out = (unsigned short*)outp;
      int row = lane & 31, half = lane >> 5;
      int mbase = m0 + 64 * wr;
      int b = mbase >> 11, s = mbase & (S_LEN - 1);
      #pragma unroll
      for (int i = 0; i < 4; ++i) {
        int ch = 4 * half + i;
        uint4 v = *(const uint4*)(tb + 144 * row + 16 * ch);
        *(uint4*)(out + ((size_t)(b * NH + h) * 64 + 32 * wc + row) * S_LEN + s + 8 * ch) = v;
      }
    }
  }
}

// ---------------- attention ----------------
__global__ __launch_bounds__(256)
void attn_mfma(const unsigned short* __restrict__ Qw, const unsigned short* __restrict__ Kw,
               const unsigned short* __restrict__ Vw, unsigned short* __restrict__ Om)
{
  __shared__ char smem[24576];
  char* Kt = smem;              // [64 key][64 d] bf16 swizzled (reused as out-stage)
  char* Vt = smem + 8192;       // [64 d][64 key] bf16 swizzled (V^T tile)
  char* Et = smem + 16384;      // 4 waves x [16 q][64 key] bf16 swizzled
  const int t = threadIdx.x, wid = t >> 6, lane = t & 63;
  const int g = lane >> 4, c = lane & 15;
  int bid = blockIdx.x;
  int swz = ((bid & 7) << 7) | (bid >> 3);   // XCD swizzle (1024 % 8 == 0)
  int qb = swz & 31, bh = swz >> 5;
  const int q0 = qb * 64;
  const size_t kvbase = (size_t)bh * S_LEN * 64;

  bf16x8 aq[2];
  {
    int qrow = q0 + 16 * wid + c;
    const unsigned short* qp = Qw + kvbase + (size_t)qrow * 64 + 8 * g;
    aq[0] = ldfrag(qp);
    aq[1] = ldfrag(qp + 32);
  }
  float q2full;
  {
    float v = sumsq8(aq[0]) + sumsq8(aq[1]);
    v += __shfl_xor(v, 16); v += __shfl_xor(v, 32);
    q2full = v;                 // ||q_row c||^2
  }
  float x2r[4], Bir[4], B2r[4];
  #pragma unroll
  for (int r = 0; r < 4; ++r) {
    x2r[r] = __shfl(q2full, 4 * g + r);
    Bir[r] = 1.0f - x2r[r];
    B2r[r] = Bir[r] * Bir[r];
  }

  f32x4 oacc[4];
  #pragma unroll
  for (int i = 0; i < 4; ++i) oacc[i] = (f32x4){0.f, 0.f, 0.f, 0.f};
  float den[4] = {0.f, 0.f, 0.f, 0.f};
  char* myEt = Et + wid * 2048;

  #pragma unroll 1
  for (int kt = 0; kt < S_LEN / 64; ++kt) {
    __syncthreads();
    #pragma unroll
    for (int i = 0; i < 2; ++i) {
      int id = t + 256 * i, row = id >> 3, ch = id & 7;
      int sw = (16 * ch) ^ (16 * (row & 7));
      uint4 kv = *(const uint4*)(Kw + kvbase + (size_t)(kt * 64 + row) * 64 + 8 * ch);
      *(uint4*)(Kt + row * 128 + sw) = kv;
      uint4 vv = *(const uint4*)(Vw + (size_t)bh * 64 * S_LEN + (size_t)row * S_LEN + kt * 64 + 8 * ch);
      *(uint4*)(Vt + row * 128 + sw) = vv;
    }
    __syncthreads();

    #pragma unroll
    for (int nt = 0; nt < 4; ++nt) {
      int krow = 16 * nt + c, sw = 16 * (krow & 7);
      bf16x8 bk0 = ldfrag(Kt + krow * 128 + ((16 * g) ^ sw));
      bf16x8 bk1 = ldfrag(Kt + krow * 128 + ((64 + 16 * g) ^ sw));
      f32x4 sc = (f32x4){0.f, 0.f, 0.f, 0.f};
      sc = __builtin_amdgcn_mfma_f32_16x16x32_bf16(aq[0], bk0, sc, 0, 0, 0);
      sc = __builtin_amdgcn_mfma_f32_16x16x32_bf16(aq[1], bk1, sc, 0, 0, 0);
      float y2 = sumsq8(bk0) + sumsq8(bk1);
      y2 += __shfl_xor(y2, 16); y2 += __shfl_xor(y2, 32);   // ||k_{16nt+c}||^2
      float Cj = 1.0f + y2;
      #pragma unroll
      for (int r = 0; r < 4; ++r) {
        float xy = sc[r];
        float t2 = xy + xy;
        float A  = Cj + t2;
        float d0 = fmaf(x2r[r], y2, 1.0f) - t2;
        float dn = fmaxf(d0, 1e-10f);
        float pp = fmaf(-2.0f, Bir[r] * xy, A * x2r[r]);
        float num = fmaf(A, pp, B2r[r] * y2);
        float rd = frcp(dn);
        float mm = fmaxf(num, 0.0f) * rd * rd;
        float nn = fminf(sqrtf(mm + 1e-8f), 0.95f);
        float e  = (1.0f - nn) * frcp(1.0f + nn);
        e = sqrtf(sqrtf(sqrtf(e)));                  // == exp(-atanh(nn)/4)
        den[r] += e;
        int erow = 4 * g + r;
        *(unsigned short*)(myEt + erow * 128 + ((2 * (16 * nt + c)) ^ (16 * (erow & 7)))) = f2b(e);
      }
    }
    asm volatile("s_waitcnt lgkmcnt(0)" ::: "memory");  // in-wave Et RAW
    {
      int sw = 16 * (c & 7);
      bf16x8 ae0 = ldfrag(myEt + c * 128 + ((16 * g) ^ sw));
      bf16x8 ae1 = ldfrag(myEt + c * 128 + ((64 + 16 * g) ^ sw));
      #pragma unroll
      for (int dt = 0; dt < 4; ++dt) {
        int drow = 16 * dt + c, vs = 16 * (drow & 7);
        bf16x8 bv0 = ldfrag(Vt + drow * 128 + ((16 * g) ^ vs));
        bf16x8 bv1 = ldfrag(Vt + drow * 128 + ((64 + 16 * g) ^ vs));
        oacc[dt] = __builtin_amdgcn_mfma_f32_16x16x32_bf16(ae0, bv0, oacc[dt], 0, 0, 0);
        oacc[dt] = __builtin_amdgcn_mfma_f32_16x16x32_bf16(ae1, bv1, oacc[dt], 0, 0, 0);
      }
    }
  }

  // normalize + maps
  #pragma unroll
  for (int r = 0; r < 4; ++r) {
    float v = den[r];
    v += __shfl_xor(v, 1); v += __shfl_xor(v, 2); v += __shfl_xor(v, 4); v += __shfl_xor(v, 8);
    float rd = 1.0f / v;
    #pragma unroll
    for (int dt = 0; dt < 4; ++dt) oacc[dt][r] *= rd;
  }
  float fac[4];
  #pragma unroll
  for (int r = 0; r < 4; ++r) {
    float v = 0.f;
    #pragma unroll
    for (int dt = 0; dt < 4; ++dt) v = fmaf(oacc[dt][r], oacc[dt][r], v);
    v += __shfl_xor(v, 1); v += __shfl_xor(v, 2); v += __shfl_xor(v, 4); v += __shfl_xor(v, 8);
    float f, rn2; expmap_factor(v, f, rn2);
    fac[r] = f * logmap_factor(rn2);
  }
  __syncthreads();  // all waves done with Kt/Vt reads
  #pragma unroll
  for (int dt = 0; dt < 4; ++dt)
    #pragma unroll
    for (int r = 0; r < 4; ++r) {
      int row = 16 * wid + 4 * g + r;
      *(unsigned short*)(Kt + row * 128 + ((2 * (16 * dt + c)) ^ (16 * (row & 7)))) = f2b(oacc[dt][r] * fac[r]);
    }
  __syncthreads();
  {
    int b = bh >> 4, h = bh & 15;
    #pragma unroll
    for (int i = 0; i < 2; ++i) {
      int id = t + 256 * i, row = id >> 3, ch = id & 7;
      uint4 v = *(const uint4*)(Kt + row * 128 + ((16 * ch) ^ (16 * (row & 7))));
      *(uint4*)(Om + ((size_t)b * S_LEN + q0 + row) * DM + 64 * h + 8 * ch) = v;
    }
  }
}

extern "C" void kernel_launch(void* const* d_in, const int* in_sizes, int n_in,
                              void* d_out, int out_size, void* d_ws, size_t ws_size,
                              hipStream_t stream) {
  const float* H  = (const float*)d_in[0];
  const float* Wq = (const float*)d_in[1];
  const float* bq = (const float*)d_in[2];
  const float* Wk = (const float*)d_in[3];
  const float* bk = (const float*)d_in[4];
  const float* Wv = (const float*)d_in[5];
  const float* bv = (const float*)d_in[6];
  const float* Wo = (const float*)d_in[7];
  const float* bo = (const float*)d_in[8];

  unsigned char* ws = (unsigned char*)d_ws;
  const size_t MB = 1u << 20;
  unsigned short* Hb  = (unsigned short*)(ws);
  unsigned short* Wqb = (unsigned short*)(ws + 8 * MB);
  unsigned short* Wkb = (unsigned short*)(ws + 10 * MB);
  unsigned short* Wvb = (unsigned short*)(ws + 12 * MB);
  unsigned short* Wob = (unsigned short*)(ws + 14 * MB);
  unsigned short* Qh  = (unsigned short*)(ws + 16 * MB);
  unsigned short* Kh  = (unsigned short*)(ws + 24 * MB);
  unsigned short* Vt  = (unsigned short*)(ws + 32 * MB);
  unsigned short* Omb = (unsigned short*)(ws + 40 * MB);   // total 48 MiB

  conv_f2b<<<2048, 256, 0, stream>>>(H, (uint4*)Hb);
  conv_w4<<<dim3(512, 4), 256, 0, stream>>>(Wq, Wk, Wv, Wo,
      (uint4*)Wqb, (uint4*)Wkb, (uint4*)Wvb, (uint4*)Wob);
  dim3 gg(32, 16), gb(256);
  gemm_mfma<0><<<gg, gb, 0, stream>>>(Hb, Wqb, bq, Qh);
  gemm_mfma<1><<<gg, gb, 0, stream>>>(Hb, Wkb, bk, Kh);
  gemm_mfma<2><<<gg, gb, 0, stream>>>(Hb, Wvb, bv, Vt);
  attn_mfma<<<1024, 256, 0, stream>>>(Qh, Kh, Vt, Omb);
  gemm_mfma<3><<<gg, gb, 0, stream>>>(Omb, Wob, bo, d_out);
}

// Round 9
// 437.802 us; speedup vs baseline: 3.5942x; 1.1799x over previous
//
#include <hip/hip_runtime.h>
#include <math.h>

// R5c: R5 with HIP-safe fast-math intrinsics (__expf/__logf).
//  - row_norms pre-pass: ||q_hyp||^2, ||k_hyp||^2 from the STORED bf16 Q/K
//    -> f32 buffers (512 KB), removes per-tile norm recompute + shuffles.
//  - attn transform: e = exp(1/8*(ln(dn-m)-ln(dn+m))), m=min(sqrt(num),.95*dn)
//    == ((1-nn)/(1+nn))^(1/8); 4 transcendentals (was 6), no in-loop shuffles.
//  - GEMMs / converters unchanged from R4.

typedef short bf16x8 __attribute__((ext_vector_type(8)));
typedef float f32x4 __attribute__((ext_vector_type(4)));

static constexpr int S_LEN = 2048;
static constexpr int NH = 16;
static constexpr int DM = 1024;

__device__ __forceinline__ unsigned short f2b(float x) {
  unsigned u = __builtin_bit_cast(unsigned, x);
  return (unsigned short)((u + 0x7FFFu + ((u >> 16) & 1u)) >> 16);
}
__device__ __forceinline__ float b2f(unsigned short h) {
  unsigned u = ((unsigned)h) << 16;
  return __builtin_bit_cast(float, u);
}
__device__ __forceinline__ bf16x8 ldfrag(const void* p) {
  return __builtin_bit_cast(bf16x8, *(const uint4*)p);
}
__device__ __forceinline__ float sumsq8(bf16x8 v) {
  float s = 0.f;
  #pragma unroll
  for (int j = 0; j < 8; ++j) { float f = b2f((unsigned short)v[j]); s = fmaf(f, f, s); }
  return s;
}
__device__ __forceinline__ void expmap_factor(float nsq, float& f, float& rn2) {
  float norm   = sqrtf(nsq + 1e-8f);
  float target = fminf(tanhf(norm), 0.9f);
  float fr     = target / norm;
  float r2     = fr * fr * nsq;
  float rn     = sqrtf(r2 + 1e-8f);
  const float maxn = 1.0f - 1e-5f;
  if (rn > maxn) { fr *= maxn / rn; r2 = fr * fr * nsq; }
  f = fr; rn2 = r2;
}
__device__ __forceinline__ float logmap_factor(float nsq) {
  float norm = sqrtf(nsq + 1e-8f);
  float nc   = fminf(norm, 1.0f - 1e-5f);
  float arg  = fminf(nc, 0.99f);
  return atanhf(arg) / nc;
}

// ---------------- converters ----------------
__global__ __launch_bounds__(256)
void conv_f2b(const float* __restrict__ src, uint4* __restrict__ dst) {
  int i = blockIdx.x * 256 + threadIdx.x;
  const float4* s4 = (const float4*)src;
  float4 a = s4[2 * i], b = s4[2 * i + 1];
  uint4 o;
  o.x = (unsigned)f2b(a.x) | ((unsigned)f2b(a.y) << 16);
  o.y = (unsigned)f2b(a.z) | ((unsigned)f2b(a.w) << 16);
  o.z = (unsigned)f2b(b.x) | ((unsigned)f2b(b.y) << 16);
  o.w = (unsigned)f2b(b.z) | ((unsigned)f2b(b.w) << 16);
  dst[i] = o;
}
__global__ __launch_bounds__(256)
void conv_w4(const float* __restrict__ w0, const float* __restrict__ w1,
             const float* __restrict__ w2, const float* __restrict__ w3,
             uint4* __restrict__ d0, uint4* __restrict__ d1,
             uint4* __restrict__ d2, uint4* __restrict__ d3) {
  const float* s = blockIdx.y == 0 ? w0 : blockIdx.y == 1 ? w1 : blockIdx.y == 2 ? w2 : w3;
  uint4* d = blockIdx.y == 0 ? d0 : blockIdx.y == 1 ? d1 : blockIdx.y == 2 ? d2 : d3;
  int i = blockIdx.x * 256 + threadIdx.x;
  const float4* s4 = (const float4*)s;
  float4 a = s4[2 * i], b = s4[2 * i + 1];
  uint4 o;
  o.x = (unsigned)f2b(a.x) | ((unsigned)f2b(a.y) << 16);
  o.y = (unsigned)f2b(a.z) | ((unsigned)f2b(a.w) << 16);
  o.z = (unsigned)f2b(b.x) | ((unsigned)f2b(b.y) << 16);
  o.w = (unsigned)f2b(b.z) | ((unsigned)f2b(b.w) << 16);
  d[i] = o;
}

// ---------------- row norms: dst[row] = sum(src[row][0..63]^2), bf16 rows ----------------
__global__ __launch_bounds__(256)
void row_norms(const unsigned short* __restrict__ src, float* __restrict__ dst) {
  int t = threadIdx.x;
  int r = t >> 2, q = t & 3;
  size_t row = (size_t)blockIdx.x * 64 + r;
  const unsigned short* p = src + row * 64 + q * 16;
  bf16x8 a = ldfrag(p), b = ldfrag(p + 8);
  float v = sumsq8(a) + sumsq8(b);
  v += __shfl_xor(v, 1);
  v += __shfl_xor(v, 2);
  if (q == 0) dst[row] = v;
}

// ---------------- GEMM: out = Xb @ Wb^T + bias, epilogue per VAR ----------------
// VAR 0/1: Q/K -> exp_map -> bf16 [b,h,s,d].  VAR 2: V -> log(exp(.)) -> bf16 [b,h,d,s].
// VAR 3: plain f32 [m][1024] (final output).
// Tile: BM=128, BN=64(=1 head), BK=64. 4 waves (wr 0..1 x wc 0..1), wave tile 64x32.
template<int VAR>
__global__ __launch_bounds__(256)
void gemm_mfma(const unsigned short* __restrict__ Xb, const unsigned short* __restrict__ Wb,
               const float* __restrict__ bias, void* __restrict__ outp)
{
  __shared__ char smem[25600];
  char* Xs = smem;              // [128][64] bf16, 16KB, XOR-swizzled 16B chunks
  char* Ws = smem + 16384;      // [64][64]  bf16, 8KB
  float* nsq = (float*)(smem + 24576);  // [2][128]
  const int t = threadIdx.x, wid = t >> 6, lane = t & 63;
  const int wr = wid >> 1, wc = wid & 1;
  const int g = lane >> 4, c = lane & 15;
  const int m0 = blockIdx.x * 128, n0 = blockIdx.y * 64;

  f32x4 acc[4][2];
  #pragma unroll
  for (int i = 0; i < 4; ++i)
    #pragma unroll
    for (int j = 0; j < 2; ++j) acc[i][j] = (f32x4){0.f, 0.f, 0.f, 0.f};

  #pragma unroll 1
  for (int k0 = 0; k0 < DM; k0 += 64) {
    __syncthreads();
    #pragma unroll
    for (int i = 0; i < 4; ++i) {
      int id = t + 256 * i, row = id >> 3, ch = id & 7;
      uint4 v = *(const uint4*)(Xb + (size_t)(m0 + row) * DM + k0 + 8 * ch);
      *(uint4*)(Xs + row * 128 + ((16 * ch) ^ (16 * (row & 7)))) = v;
    }
    #pragma unroll
    for (int i = 0; i < 2; ++i) {
      int id = t + 256 * i, row = id >> 3, ch = id & 7;
      uint4 v = *(const uint4*)(Wb + (size_t)(n0 + row) * DM + k0 + 8 * ch);
      *(uint4*)(Ws + row * 128 + ((16 * ch) ^ (16 * (row & 7)))) = v;
    }
    __syncthreads();
    bf16x8 af[4][2], bfr[2][2];
    #pragma unroll
    for (int mt = 0; mt < 4; ++mt) {
      int row = 64 * wr + 16 * mt + c, sw = 16 * (row & 7);
      af[mt][0] = ldfrag(Xs + row * 128 + ((16 * g) ^ sw));
      af[mt][1] = ldfrag(Xs + row * 128 + ((64 + 16 * g) ^ sw));
    }
    #pragma unroll
    for (int nt = 0; nt < 2; ++nt) {
      int row = 32 * wc + 16 * nt + c, sw = 16 * (row & 7);
      bfr[nt][0] = ldfrag(Ws + row * 128 + ((16 * g) ^ sw));
      bfr[nt][1] = ldfrag(Ws + row * 128 + ((64 + 16 * g) ^ sw));
    }
    #pragma unroll
    for (int mt = 0; mt < 4; ++mt)
      #pragma unroll
      for (int nt = 0; nt < 2; ++nt) {
        acc[mt][nt] = __builtin_amdgcn_mfma_f32_16x16x32_bf16(af[mt][0], bfr[nt][0], acc[mt][nt], 0, 0, 0);
        acc[mt][nt] = __builtin_amdgcn_mfma_f32_16x16x32_bf16(af[mt][1], bfr[nt][1], acc[mt][nt], 0, 0, 0);
      }
  }

  float bv[2];
  #pragma unroll
  for (int nt = 0; nt < 2; ++nt) bv[nt] = bias[n0 + 32 * wc + 16 * nt + c];
  #pragma unroll
  for (int mt = 0; mt < 4; ++mt)
    #pragma unroll
    for (int nt = 0; nt < 2; ++nt)
      #pragma unroll
      for (int r = 0; r < 4; ++r) acc[mt][nt][r] += bv[nt];

  if constexpr (VAR == 3) {
    float* out = (float*)outp;
    #pragma unroll
    for (int mt = 0; mt < 4; ++mt)
      #pragma unroll
      for (int nt = 0; nt < 2; ++nt)
        #pragma unroll
        for (int r = 0; r < 4; ++r) {
          int m = m0 + 64 * wr + 16 * mt + 4 * g + r;
          out[(size_t)m * DM + n0 + 32 * wc + 16 * nt + c] = acc[mt][nt][r];
        }
    return;
  } else {
    // row ||.||^2: intra-wave over 32 cols, cross-wave (wc pair) via LDS
    float p[4][4];
    #pragma unroll
    for (int mt = 0; mt < 4; ++mt)
      #pragma unroll
      for (int r = 0; r < 4; ++r) {
        float v = acc[mt][0][r] * acc[mt][0][r] + acc[mt][1][r] * acc[mt][1][r];
        v += __shfl_xor(v, 1); v += __shfl_xor(v, 2); v += __shfl_xor(v, 4); v += __shfl_xor(v, 8);
        p[mt][r] = v;
      }
    __syncthreads();
    if (c == 0) {
      #pragma unroll
      for (int mt = 0; mt < 4; ++mt)
        #pragma unroll
        for (int r = 0; r < 4; ++r)
          nsq[wc * 128 + 64 * wr + 16 * mt + 4 * g + r] = p[mt][r];
    }
    __syncthreads();
    float fac[4][4];
    #pragma unroll
    for (int mt = 0; mt < 4; ++mt)
      #pragma unroll
      for (int r = 0; r < 4; ++r) {
        int row = 64 * wr + 16 * mt + 4 * g + r;
        float v = nsq[row] + nsq[128 + row];
        float f, rn2; expmap_factor(v, f, rn2);
        if (VAR == 2) f *= logmap_factor(rn2);
        fac[mt][r] = f;
      }
    const int h = (int)blockIdx.y;   // BN=64 == one head
    if constexpr (VAR != 2) {
      unsigned short* out = (unsigned short*)outp;
      #pragma unroll
      for (int mt = 0; mt < 4; ++mt)
        #pragma unroll
        for (int nt = 0; nt < 2; ++nt)
          #pragma unroll
          for (int r = 0; r < 4; ++r) {
            int m = m0 + 64 * wr + 16 * mt + 4 * g + r;
            int b = m >> 11, s = m & (S_LEN - 1);
            int d = 32 * wc + 16 * nt + c;
            out[((size_t)(b * NH + h) * S_LEN + s) * 64 + d] = f2b(acc[mt][nt][r] * fac[mt][r]);
          }
    } else {
      // transpose via padded LDS [32 d][72 bf16], per-wave region (overlaps Xs/Ws: synced above)
      char* tb = smem + wid * 4608;
      #pragma unroll
      for (int mt = 0; mt < 4; ++mt)
        #pragma unroll
        for (int nt = 0; nt < 2; ++nt)
          #pragma unroll
          for (int r = 0; r < 4; ++r) {
            int d = 16 * nt + c, sl = 16 * mt + 4 * g + r;
            *(unsigned short*)(tb + 144 * d + 2 * sl) = f2b(acc[mt][nt][r] * fac[mt][r]);
          }
      asm volatile("s_waitcnt lgkmcnt(0)" ::: "memory");
      unsigned short* out = (unsigned short*)outp;
      int row = lane & 31, half = lane >> 5;
      int mbase = m0 + 64 * wr;
      int b = mbase >> 11, s = mbase & (S_LEN - 1);
      #pragma unroll
      for (int i = 0; i < 4; ++i) {
        int ch = 4 * half + i;
        uint4 v = *(const uint4*)(tb + 144 * row + 16 * ch);
        *(uint4*)(out + ((size_t)(b * NH + h) * 64 + 32 * wc + row) * S_LEN + s + 8 * ch) = v;
      }
    }
  }
}

// ---------------- attention ----------------
__global__ __launch_bounds__(256)
void attn_mfma(const unsigned short* __restrict__ Qw, const unsigned short* __restrict__ Kw,
               const unsigned short* __restrict__ Vw, const float* __restrict__ q2g,
               const float* __restrict__ k2g, unsigned short* __restrict__ Om)
{
  __shared__ char smem[24832];
  char* Kt = smem;              // [64 key][64 d] bf16 swizzled (reused as out-stage)
  char* Vt = smem + 8192;       // [64 d][64 key] bf16 swizzled (V^T tile)
  char* Et = smem + 16384;      // 4 waves x [16 q][64 key] bf16 swizzled
  float* k2s = (float*)(smem + 24576);  // [64]
  const int t = threadIdx.x, wid = t >> 6, lane = t & 63;
  const int g = lane >> 4, c = lane & 15;
  int bid = blockIdx.x;
  int swz = ((bid & 7) << 7) | (bid >> 3);   // XCD swizzle (1024 % 8 == 0)
  int qb = swz & 31, bh = swz >> 5;
  const int q0 = qb * 64;
  const size_t kvbase = (size_t)bh * S_LEN * 64;

  bf16x8 aq[2];
  {
    int qrow = q0 + 16 * wid + c;
    const unsigned short* qp = Qw + kvbase + (size_t)qrow * 64 + 8 * g;
    aq[0] = ldfrag(qp);
    aq[1] = ldfrag(qp + 32);
  }
  float x2r[4], Bir[4], B2r[4];
  #pragma unroll
  for (int r = 0; r < 4; ++r) {
    x2r[r] = q2g[(size_t)bh * S_LEN + q0 + 16 * wid + 4 * g + r];
    Bir[r] = 1.0f - x2r[r];
    B2r[r] = Bir[r] * Bir[r];
  }

  f32x4 oacc[4];
  #pragma unroll
  for (int i = 0; i < 4; ++i) oacc[i] = (f32x4){0.f, 0.f, 0.f, 0.f};
  float den[4] = {0.f, 0.f, 0.f, 0.f};
  char* myEt = Et + wid * 2048;

  #pragma unroll 1
  for (int kt = 0; kt < S_LEN / 64; ++kt) {
    __syncthreads();
    #pragma unroll
    for (int i = 0; i < 2; ++i) {
      int id = t + 256 * i, row = id >> 3, ch = id & 7;
      int sw = (16 * ch) ^ (16 * (row & 7));
      uint4 kv = *(const uint4*)(Kw + kvbase + (size_t)(kt * 64 + row) * 64 + 8 * ch);
      *(uint4*)(Kt + row * 128 + sw) = kv;
      uint4 vv = *(const uint4*)(Vw + (size_t)bh * 64 * S_LEN + (size_t)row * S_LEN + kt * 64 + 8 * ch);
      *(uint4*)(Vt + row * 128 + sw) = vv;
    }
    if (t < 16) {
      float4 kv2 = *(const float4*)(k2g + (size_t)bh * S_LEN + kt * 64 + 4 * t);
      *(float4*)(k2s + 4 * t) = kv2;
    }
    __syncthreads();

    #pragma unroll
    for (int nt = 0; nt < 4; ++nt) {
      int krow = 16 * nt + c, sw = 16 * (krow & 7);
      bf16x8 bk0 = ldfrag(Kt + krow * 128 + ((16 * g) ^ sw));
      bf16x8 bk1 = ldfrag(Kt + krow * 128 + ((64 + 16 * g) ^ sw));
      f32x4 sc = (f32x4){0.f, 0.f, 0.f, 0.f};
      sc = __builtin_amdgcn_mfma_f32_16x16x32_bf16(aq[0], bk0, sc, 0, 0, 0);
      sc = __builtin_amdgcn_mfma_f32_16x16x32_bf16(aq[1], bk1, sc, 0, 0, 0);
      float y2 = k2s[16 * nt + c];
      float Cj = 1.0f + y2;
      #pragma unroll
      for (int r = 0; r < 4; ++r) {
        float xy = sc[r];
        float t2 = xy + xy;
        float A  = Cj + t2;
        float dn = fmaxf(fmaf(x2r[r], y2, 1.0f) - t2, 1e-10f);
        float pp = fmaf(-2.0f, Bir[r] * xy, A * x2r[r]);
        float num = fmaxf(fmaf(A, pp, B2r[r] * y2), 0.0f);
        float s_ = sqrtf(num);
        float m_ = fminf(s_, 0.95f * dn);
        // e = ((dn-m)/(dn+m))^(1/8) == ((1-nn)/(1+nn))^(1/8), nn = m/dn
        float e = __expf(0.125f * (__logf(dn - m_) - __logf(dn + m_)));
        den[r] += e;
        int erow = 4 * g + r;
        *(unsigned short*)(myEt + erow * 128 + ((2 * (16 * nt + c)) ^ (16 * (erow & 7)))) = f2b(e);
      }
    }
    asm volatile("s_waitcnt lgkmcnt(0)" ::: "memory");  // in-wave Et RAW
    {
      int sw = 16 * (c & 7);
      bf16x8 ae0 = ldfrag(myEt + c * 128 + ((16 * g) ^ sw));
      bf16x8 ae1 = ldfrag(myEt + c * 128 + ((64 + 16 * g) ^ sw));
      #pragma unroll
      for (int dt = 0; dt < 4; ++dt) {
        int drow = 16 * dt + c, vs = 16 * (drow & 7);
        bf16x8 bv0 = ldfrag(Vt + drow * 128 + ((16 * g) ^ vs));
        bf16x8 bv1 = ldfrag(Vt + drow * 128 + ((64 + 16 * g) ^ vs));
        oacc[dt] = __builtin_amdgcn_mfma_f32_16x16x32_bf16(ae0, bv0, oacc[dt], 0, 0, 0);
        oacc[dt] = __builtin_amdgcn_mfma_f32_16x16x32_bf16(ae1, bv1, oacc[dt], 0, 0, 0);
      }
    }
  }

  // normalize + maps
  #pragma unroll
  for (int r = 0; r < 4; ++r) {
    float v = den[r];
    v += __shfl_xor(v, 1); v += __shfl_xor(v, 2); v += __shfl_xor(v, 4); v += __shfl_xor(v, 8);
    float rd = 1.0f / v;
    #pragma unroll
    for (int dt = 0; dt < 4; ++dt) oacc[dt][r] *= rd;
  }
  float fac[4];
  #pragma unroll
  for (int r = 0; r < 4; ++r) {
    float v = 0.f;
    #pragma unroll
    for (int dt = 0; dt < 4; ++dt) v = fmaf(oacc[dt][r], oacc[dt][r], v);
    v += __shfl_xor(v, 1); v += __shfl_xor(v, 2); v += __shfl_xor(v, 4); v += __shfl_xor(v, 8);
    float f, rn2; expmap_factor(v, f, rn2);
    fac[r] = f * logmap_factor(rn2);
  }
  __syncthreads();  // all waves done with Kt/Vt reads
  #pragma unroll
  for (int dt = 0; dt < 4; ++dt)
    #pragma unroll
    for (int r = 0; r < 4; ++r) {
      int row = 16 * wid + 4 * g + r;
      *(unsigned short*)(Kt + row * 128 + ((2 * (16 * dt + c)) ^ (16 * (row & 7)))) = f2b(oacc[dt][r] * fac[r]);
    }
  __syncthreads();
  {
    int b = bh >> 4, h = bh & 15;
    #pragma unroll
    for (int i = 0; i < 2; ++i) {
      int id = t + 256 * i, row = id >> 3, ch = id & 7;
      uint4 v = *(const uint4*)(Kt + row * 128 + ((16 * ch) ^ (16 * (row & 7))));
      *(uint4*)(Om + ((size_t)b * S_LEN + q0 + row) * DM + 64 * h + 8 * ch) = v;
    }
  }
}

extern "C" void kernel_launch(void* const* d_in, const int* in_sizes, int n_in,
                              void* d_out, int out_size, void* d_ws, size_t ws_size,
                              hipStream_t stream) {
  const float* H  = (const float*)d_in[0];
  const float* Wq = (const float*)d_in[1];
  const float* bq = (const float*)d_in[2];
  const float* Wk = (const float*)d_in[3];
  const float* bk = (const float*)d_in[4];
  const float* Wv = (const float*)d_in[5];
  const float* bv = (const float*)d_in[6];
  const float* Wo = (const float*)d_in[7];
  const float* bo = (const float*)d_in[8];

  unsigned char* ws = (unsigned char*)d_ws;
  const size_t MB = 1u << 20;
  unsigned short* Hb  = (unsigned short*)(ws);
  unsigned short* Wqb = (unsigned short*)(ws + 8 * MB);
  unsigned short* Wkb = (unsigned short*)(ws + 10 * MB);
  unsigned short* Wvb = (unsigned short*)(ws + 12 * MB);
  unsigned short* Wob = (unsigned short*)(ws + 14 * MB);
  unsigned short* Qh  = (unsigned short*)(ws + 16 * MB);
  unsigned short* Kh  = (unsigned short*)(ws + 24 * MB);
  unsigned short* Vt  = (unsigned short*)(ws + 32 * MB);
  unsigned short* Omb = (unsigned short*)(ws + 40 * MB);
  float*          q2  = (float*)(ws + 48 * MB);            // 256 KB
  float*          k2  = q2 + (size_t)2 * NH * S_LEN;       // 256 KB -> total 48.5 MiB

  conv_f2b<<<2048, 256, 0, stream>>>(H, (uint4*)Hb);
  conv_w4<<<dim3(512, 4), 256, 0, stream>>>(Wq, Wk, Wv, Wo,
      (uint4*)Wqb, (uint4*)Wkb, (uint4*)Wvb, (uint4*)Wob);
  dim3 gg(32, 16), gb(256);
  gemm_mfma<0><<<gg, gb, 0, stream>>>(Hb, Wqb, bq, Qh);
  gemm_mfma<1><<<gg, gb, 0, stream>>>(Hb, Wkb, bk, Kh);
  gemm_mfma<2><<<gg, gb, 0, stream>>>(Hb, Wvb, bv, Vt);
  // Qh and Kh are contiguous (16..32 MB); q2,k2 contiguous too -> one pass
  row_norms<<<2048, 256, 0, stream>>>(Qh, q2);
  attn_mfma<<<1024, 256, 0, stream>>>(Qh, Kh, Vt, q2, k2, Omb);
  gemm_mfma<3><<<gg, gb, 0, stream>>>(Omb, Wob, bo, d_out);
}

// Round 11
// 338.282 us; speedup vs baseline: 4.6515x; 1.2942x over previous
//
#include <hip/hip_runtime.h>
#include <math.h>

// R6: attn inner-loop lean-down.
//  - score transform via 512-entry LDS table f(mm), mm = num/dn^2 (1 rcp, no sqrt/log/exp)
//    table built per-block from the exact reference formula (incl +1e-8 eps, 0.95 clamp)
//  - all kt-invariant swizzled LDS addresses precomputed before the loop
//  - e -> bf16 via v_cvt_pk_bf16_f32 (RNE, matches f2b)
//  - GEMMs / converters / row_norms unchanged from R5c.

typedef short bf16x8 __attribute__((ext_vector_type(8)));
typedef float f32x4 __attribute__((ext_vector_type(4)));

static constexpr int S_LEN = 2048;
static constexpr int NH = 16;
static constexpr int DM = 1024;

__device__ __forceinline__ unsigned short f2b(float x) {
  unsigned u = __builtin_bit_cast(unsigned, x);
  return (unsigned short)((u + 0x7FFFu + ((u >> 16) & 1u)) >> 16);
}
__device__ __forceinline__ float b2f(unsigned short h) {
  unsigned u = ((unsigned)h) << 16;
  return __builtin_bit_cast(float, u);
}
__device__ __forceinline__ bf16x8 ldfrag(const void* p) {
  return __builtin_bit_cast(bf16x8, *(const uint4*)p);
}
__device__ __forceinline__ float sumsq8(bf16x8 v) {
  float s = 0.f;
  #pragma unroll
  for (int j = 0; j < 8; ++j) { float f = b2f((unsigned short)v[j]); s = fmaf(f, f, s); }
  return s;
}
__device__ __forceinline__ void expmap_factor(float nsq, float& f, float& rn2) {
  float norm   = sqrtf(nsq + 1e-8f);
  float target = fminf(tanhf(norm), 0.9f);
  float fr     = target / norm;
  float r2     = fr * fr * nsq;
  float rn     = sqrtf(r2 + 1e-8f);
  const float maxn = 1.0f - 1e-5f;
  if (rn > maxn) { fr *= maxn / rn; r2 = fr * fr * nsq; }
  f = fr; rn2 = r2;
}
__device__ __forceinline__ float logmap_factor(float nsq) {
  float norm = sqrtf(nsq + 1e-8f);
  float nc   = fminf(norm, 1.0f - 1e-5f);
  float arg  = fminf(nc, 0.99f);
  return atanhf(arg) / nc;
}

// ---------------- converters ----------------
__global__ __launch_bounds__(256)
void conv_f2b(const float* __restrict__ src, uint4* __restrict__ dst) {
  int i = blockIdx.x * 256 + threadIdx.x;
  const float4* s4 = (const float4*)src;
  float4 a = s4[2 * i], b = s4[2 * i + 1];
  uint4 o;
  o.x = (unsigned)f2b(a.x) | ((unsigned)f2b(a.y) << 16);
  o.y = (unsigned)f2b(a.z) | ((unsigned)f2b(a.w) << 16);
  o.z = (unsigned)f2b(b.x) | ((unsigned)f2b(b.y) << 16);
  o.w = (unsigned)f2b(b.z) | ((unsigned)f2b(b.w) << 16);
  dst[i] = o;
}
__global__ __launch_bounds__(256)
void conv_w4(const float* __restrict__ w0, const float* __restrict__ w1,
             const float* __restrict__ w2, const float* __restrict__ w3,
             uint4* __restrict__ d0, uint4* __restrict__ d1,
             uint4* __restrict__ d2, uint4* __restrict__ d3) {
  const float* s = blockIdx.y == 0 ? w0 : blockIdx.y == 1 ? w1 : blockIdx.y == 2 ? w2 : w3;
  uint4* d = blockIdx.y == 0 ? d0 : blockIdx.y == 1 ? d1 : blockIdx.y == 2 ? d2 : d3;
  int i = blockIdx.x * 256 + threadIdx.x;
  const float4* s4 = (const float4*)s;
  float4 a = s4[2 * i], b = s4[2 * i + 1];
  uint4 o;
  o.x = (unsigned)f2b(a.x) | ((unsigned)f2b(a.y) << 16);
  o.y = (unsigned)f2b(a.z) | ((unsigned)f2b(a.w) << 16);
  o.z = (unsigned)f2b(b.x) | ((unsigned)f2b(b.y) << 16);
  o.w = (unsigned)f2b(b.z) | ((unsigned)f2b(b.w) << 16);
  d[i] = o;
}

// ---------------- row norms ----------------
__global__ __launch_bounds__(256)
void row_norms(const unsigned short* __restrict__ src, float* __restrict__ dst) {
  int t = threadIdx.x;
  int r = t >> 2, q = t & 3;
  size_t row = (size_t)blockIdx.x * 64 + r;
  const unsigned short* p = src + row * 64 + q * 16;
  bf16x8 a = ldfrag(p), b = ldfrag(p + 8);
  float v = sumsq8(a) + sumsq8(b);
  v += __shfl_xor(v, 1);
  v += __shfl_xor(v, 2);
  if (q == 0) dst[row] = v;
}

// ---------------- GEMM (unchanged from R5c) ----------------
template<int VAR>
__global__ __launch_bounds__(256)
void gemm_mfma(const unsigned short* __restrict__ Xb, const unsigned short* __restrict__ Wb,
               const float* __restrict__ bias, void* __restrict__ outp)
{
  __shared__ char smem[25600];
  char* Xs = smem;
  char* Ws = smem + 16384;
  float* nsq = (float*)(smem + 24576);
  const int t = threadIdx.x, wid = t >> 6, lane = t & 63;
  const int wr = wid >> 1, wc = wid & 1;
  const int g = lane >> 4, c = lane & 15;
  const int m0 = blockIdx.x * 128, n0 = blockIdx.y * 64;

  f32x4 acc[4][2];
  #pragma unroll
  for (int i = 0; i < 4; ++i)
    #pragma unroll
    for (int j = 0; j < 2; ++j) acc[i][j] = (f32x4){0.f, 0.f, 0.f, 0.f};

  #pragma unroll 1
  for (int k0 = 0; k0 < DM; k0 += 64) {
    __syncthreads();
    #pragma unroll
    for (int i = 0; i < 4; ++i) {
      int id = t + 256 * i, row = id >> 3, ch = id & 7;
      uint4 v = *(const uint4*)(Xb + (size_t)(m0 + row) * DM + k0 + 8 * ch);
      *(uint4*)(Xs + row * 128 + ((16 * ch) ^ (16 * (row & 7)))) = v;
    }
    #pragma unroll
    for (int i = 0; i < 2; ++i) {
      int id = t + 256 * i, row = id >> 3, ch = id & 7;
      uint4 v = *(const uint4*)(Wb + (size_t)(n0 + row) * DM + k0 + 8 * ch);
      *(uint4*)(Ws + row * 128 + ((16 * ch) ^ (16 * (row & 7)))) = v;
    }
    __syncthreads();
    bf16x8 af[4][2], bfr[2][2];
    #pragma unroll
    for (int mt = 0; mt < 4; ++mt) {
      int row = 64 * wr + 16 * mt + c, sw = 16 * (row & 7);
      af[mt][0] = ldfrag(Xs + row * 128 + ((16 * g) ^ sw));
      af[mt][1] = ldfrag(Xs + row * 128 + ((64 + 16 * g) ^ sw));
    }
    #pragma unroll
    for (int nt = 0; nt < 2; ++nt) {
      int row = 32 * wc + 16 * nt + c, sw = 16 * (row & 7);
      bfr[nt][0] = ldfrag(Ws + row * 128 + ((16 * g) ^ sw));
      bfr[nt][1] = ldfrag(Ws + row * 128 + ((64 + 16 * g) ^ sw));
    }
    #pragma unroll
    for (int mt = 0; mt < 4; ++mt)
      #pragma unroll
      for (int nt = 0; nt < 2; ++nt) {
        acc[mt][nt] = __builtin_amdgcn_mfma_f32_16x16x32_bf16(af[mt][0], bfr[nt][0], acc[mt][nt], 0, 0, 0);
        acc[mt][nt] = __builtin_amdgcn_mfma_f32_16x16x32_bf16(af[mt][1], bfr[nt][1], acc[mt][nt], 0, 0, 0);
      }
  }

  float bv[2];
  #pragma unroll
  for (int nt = 0; nt < 2; ++nt) bv[nt] = bias[n0 + 32 * wc + 16 * nt + c];
  #pragma unroll
  for (int mt = 0; mt < 4; ++mt)
    #pragma unroll
    for (int nt = 0; nt < 2; ++nt)
      #pragma unroll
      for (int r = 0; r < 4; ++r) acc[mt][nt][r] += bv[nt];

  if constexpr (VAR == 3) {
    float* out = (float*)outp;
    #pragma unroll
    for (int mt = 0; mt < 4; ++mt)
      #pragma unroll
      for (int nt = 0; nt < 2; ++nt)
        #pragma unroll
        for (int r = 0; r < 4; ++r) {
          int m = m0 + 64 * wr + 16 * mt + 4 * g + r;
          out[(size_t)m * DM + n0 + 32 * wc + 16 * nt + c] = acc[mt][nt][r];
        }
    return;
  } else {
    float p[4][4];
    #pragma unroll
    for (int mt = 0; mt < 4; ++mt)
      #pragma unroll
      for (int r = 0; r < 4; ++r) {
        float v = acc[mt][0][r] * acc[mt][0][r] + acc[mt][1][r] * acc[mt][1][r];
        v += __shfl_xor(v, 1); v += __shfl_xor(v, 2); v += __shfl_xor(v, 4); v += __shfl_xor(v, 8);
        p[mt][r] = v;
      }
    __syncthreads();
    if (c == 0) {
      #pragma unroll
      for (int mt = 0; mt < 4; ++mt)
        #pragma unroll
        for (int r = 0; r < 4; ++r)
          nsq[wc * 128 + 64 * wr + 16 * mt + 4 * g + r] = p[mt][r];
    }
    __syncthreads();
    float fac[4][4];
    #pragma unroll
    for (int mt = 0; mt < 4; ++mt)
      #pragma unroll
      for (int r = 0; r < 4; ++r) {
        int row = 64 * wr + 16 * mt + 4 * g + r;
        float v = nsq[row] + nsq[128 + row];
        float f, rn2; expmap_factor(v, f, rn2);
        if (VAR == 2) f *= logmap_factor(rn2);
        fac[mt][r] = f;
      }
    const int h = (int)blockIdx.y;
    if constexpr (VAR != 2) {
      unsigned short* out = (unsigned short*)outp;
      #pragma unroll
      for (int mt = 0; mt < 4; ++mt)
        #pragma unroll
        for (int nt = 0; nt < 2; ++nt)
          #pragma unroll
          for (int r = 0; r < 4; ++r) {
            int m = m0 + 64 * wr + 16 * mt + 4 * g + r;
            int b = m >> 11, s = m & (S_LEN - 1);
            int d = 32 * wc + 16 * nt + c;
            out[((size_t)(b * NH + h) * S_LEN + s) * 64 + d] = f2b(acc[mt][nt][r] * fac[mt][r]);
          }
    } else {
      char* tb = smem + wid * 4608;
      #pragma unroll
      for (int mt = 0; mt < 4; ++mt)
        #pragma unroll
        for (int nt = 0; nt < 2; ++nt)
          #pragma unroll
          for (int r = 0; r < 4; ++r) {
            int d = 16 * nt + c, sl = 16 * mt + 4 * g + r;
            *(unsigned short*)(tb + 144 * d + 2 * sl) = f2b(acc[mt][nt][r] * fac[mt][r]);
          }
      asm volatile("s_waitcnt lgkmcnt(0)" ::: "memory");
      unsigned short* out = (unsigned short*)outp;
      int row = lane & 31, half = lane >> 5;
      int mbase = m0 + 64 * wr;
      int b = mbase >> 11, s = mbase & (S_LEN - 1);
      #pragma unroll
      for (int i = 0; i < 4; ++i) {
        int ch = 4 * half + i;
        uint4 v = *(const uint4*)(tb + 144 * row + 16 * ch);
        *(uint4*)(out + ((size_t)(b * NH + h) * 64 + 32 * wc + row) * S_LEN + s + 8 * ch) = v;
      }
    }
  }
}

// ---------------- attention ----------------
// LDS layout: Kt 0..8192 | Vt 8192..16384 | Et 16384..24576 (4x2048)
//             k2s 24576..24832 | table 24832..28928 (512 x {f, slope})
__global__ __launch_bounds__(256)
void attn_mfma(const unsigned short* __restrict__ Qw, const unsigned short* __restrict__ Kw,
               const unsigned short* __restrict__ Vw, const float* __restrict__ q2g,
               const float* __restrict__ k2g, unsigned short* __restrict__ Om)
{
  __shared__ char smem[28928];
  const int K2OFF = 24576, TABOFF = 24832;
  const int t = threadIdx.x, wid = t >> 6, lane = t & 63;
  const int g = lane >> 4, c = lane & 15;
  int bid = blockIdx.x;
  int swz = ((bid & 7) << 7) | (bid >> 3);   // XCD swizzle (1024 % 8 == 0)
  int qb = swz & 31, bh = swz >> 5;
  const int q0 = qb * 64;
  const size_t kvbase = (size_t)bh * S_LEN * 64;

  // ---- build e(mm) table: mm = mob2, f = exp(-atanh(min(sqrt(mm+1e-8),0.95))/4)
  {
    const float DLT = 0.9025f / 512.0f;
    #pragma unroll
    for (int jj = 0; jj < 2; ++jj) {
      int j = t + 256 * jj;
      float m0 = j * DLT, m1 = m0 + DLT;
      float s0 = fminf(sqrtf(m0 + 1e-8f), 0.95f);
      float s1 = fminf(sqrtf(m1 + 1e-8f), 0.95f);
      float f0 = expf(0.125f * (logf(1.0f - s0) - logf(1.0f + s0)));
      float f1 = expf(0.125f * (logf(1.0f - s1) - logf(1.0f + s1)));
      float2 pr; pr.x = f0; pr.y = f1 - f0;
      *(float2*)(smem + TABOFF + 8 * j) = pr;
    }
  }

  // ---- kt-invariant addresses
  const int eoff = 16384 + wid * 2048;
  int ewa[4][4];
  #pragma unroll
  for (int r = 0; r < 4; ++r) {
    int erow = 4 * g + r;
    int mask = 16 * (erow & 7);
    #pragma unroll
    for (int nt = 0; nt < 4; ++nt)
      ewa[r][nt] = eoff + erow * 128 + ((2 * (16 * nt + c)) ^ mask);
  }
  int kra[4][2];
  #pragma unroll
  for (int nt = 0; nt < 4; ++nt) {
    int krow = 16 * nt + c, sw = 16 * (krow & 7);
    kra[nt][0] = krow * 128 + ((16 * g) ^ sw);
    kra[nt][1] = krow * 128 + ((64 + 16 * g) ^ sw);
  }
  int era0, era1;
  { int sw = 16 * (c & 7);
    era0 = eoff + c * 128 + ((16 * g) ^ sw);
    era1 = eoff + c * 128 + ((64 + 16 * g) ^ sw); }
  int swa[2];
  #pragma unroll
  for (int i = 0; i < 2; ++i) {
    int id = t + 256 * i, row = id >> 3, ch = id & 7;
    swa[i] = row * 128 + ((16 * ch) ^ (16 * (row & 7)));
  }
  const int k2ca = K2OFF + 4 * c;

  // ---- Q fragments + per-row scalars
  bf16x8 aq[2];
  {
    int qrow = q0 + 16 * wid + c;
    const unsigned short* qp = Qw + kvbase + (size_t)qrow * 64 + 8 * g;
    aq[0] = ldfrag(qp);
    aq[1] = ldfrag(qp + 32);
  }
  float x2r[4], Bir[4], B2r[4];
  #pragma unroll
  for (int r = 0; r < 4; ++r) {
    x2r[r] = q2g[(size_t)bh * S_LEN + q0 + 16 * wid + 4 * g + r];
    Bir[r] = 1.0f - x2r[r];
    B2r[r] = Bir[r] * Bir[r];
  }

  f32x4 oacc[4];
  #pragma unroll
  for (int i = 0; i < 4; ++i) oacc[i] = (f32x4){0.f, 0.f, 0.f, 0.f};
  float den[4] = {0.f, 0.f, 0.f, 0.f};
  const float TSCL = 512.0f / 0.9025f;

  #pragma unroll 1
  for (int kt = 0; kt < S_LEN / 64; ++kt) {
    __syncthreads();
    #pragma unroll
    for (int i = 0; i < 2; ++i) {
      int id = t + 256 * i, row = id >> 3, ch = id & 7;
      uint4 kv = *(const uint4*)(Kw + kvbase + (size_t)(kt * 64 + row) * 64 + 8 * ch);
      *(uint4*)(smem + swa[i]) = kv;
      uint4 vv = *(const uint4*)(Vw + (size_t)bh * 64 * S_LEN + (size_t)row * S_LEN + kt * 64 + 8 * ch);
      *(uint4*)(smem + 8192 + swa[i]) = vv;
    }
    if (t < 16) {
      float4 kv2 = *(const float4*)(k2g + (size_t)bh * S_LEN + kt * 64 + 4 * t);
      *(float4*)(smem + K2OFF + 16 * t) = kv2;
    }
    __syncthreads();

    #pragma unroll
    for (int nt = 0; nt < 4; ++nt) {
      bf16x8 bk0 = ldfrag(smem + kra[nt][0]);
      bf16x8 bk1 = ldfrag(smem + kra[nt][1]);
      f32x4 sc = (f32x4){0.f, 0.f, 0.f, 0.f};
      sc = __builtin_amdgcn_mfma_f32_16x16x32_bf16(aq[0], bk0, sc, 0, 0, 0);
      sc = __builtin_amdgcn_mfma_f32_16x16x32_bf16(aq[1], bk1, sc, 0, 0, 0);
      float y2 = *(const float*)(smem + k2ca + 64 * nt);
      float Cj = 1.0f + y2;
      float ev[4];
      #pragma unroll
      for (int r = 0; r < 4; ++r) {
        float xy = sc[r];
        float t2 = xy + xy;
        float A  = Cj + t2;
        float dn = fmaxf(fmaf(x2r[r], y2, 1.0f) - t2, 1e-10f);
        float pp = fmaf(-2.0f, Bir[r] * xy, A * x2r[r]);
        float num = fmaxf(fmaf(A, pp, B2r[r] * y2), 0.0f);
        float rdn; asm("v_rcp_f32 %0, %1" : "=v"(rdn) : "v"(dn));
        float mm = num * rdn * rdn;
        float ti_ = fminf(mm * TSCL, 511.99994f);
        int   ii = (int)ti_;
        float fr_ = ti_ - (float)ii;
        float2 pr = *(const float2*)(smem + TABOFF + 8 * ii);
        float e = fmaf(fr_, pr.y, pr.x);
        den[r] += e;
        ev[r] = e;
      }
      unsigned p01, p23;
      asm("v_cvt_pk_bf16_f32 %0, %1, %2" : "=v"(p01) : "v"(ev[0]), "v"(ev[1]));
      asm("v_cvt_pk_bf16_f32 %0, %1, %2" : "=v"(p23) : "v"(ev[2]), "v"(ev[3]));
      *(unsigned short*)(smem + ewa[0][nt]) = (unsigned short)p01;
      *(unsigned short*)(smem + ewa[1][nt]) = (unsigned short)(p01 >> 16);
      *(unsigned short*)(smem + ewa[2][nt]) = (unsigned short)p23;
      *(unsigned short*)(smem + ewa[3][nt]) = (unsigned short)(p23 >> 16);
    }
    asm volatile("s_waitcnt lgkmcnt(0)" ::: "memory");  // in-wave Et RAW
    {
      bf16x8 ae0 = ldfrag(smem + era0);
      bf16x8 ae1 = ldfrag(smem + era1);
      #pragma unroll
      for (int dt = 0; dt < 4; ++dt) {
        bf16x8 bv0 = ldfrag(smem + 8192 + kra[dt][0]);
        bf16x8 bv1 = ldfrag(smem + 8192 + kra[dt][1]);
        oacc[dt] = __builtin_amdgcn_mfma_f32_16x16x32_bf16(ae0, bv0, oacc[dt], 0, 0, 0);
        oacc[dt] = __builtin_amdgcn_mfma_f32_16x16x32_bf16(ae1, bv1, oacc[dt], 0, 0, 0);
      }
    }
  }

  // normalize + maps
  #pragma unroll
  for (int r = 0; r < 4; ++r) {
    float v = den[r];
    v += __shfl_xor(v, 1); v += __shfl_xor(v, 2); v += __shfl_xor(v, 4); v += __shfl_xor(v, 8);
    float rd = 1.0f / v;
    #pragma unroll
    for (int dt = 0; dt < 4; ++dt) oacc[dt][r] *= rd;
  }
  float fac[4];
  #pragma unroll
  for (int r = 0; r < 4; ++r) {
    float v = 0.f;
    #pragma unroll
    for (int dt = 0; dt < 4; ++dt) v = fmaf(oacc[dt][r], oacc[dt][r], v);
    v += __shfl_xor(v, 1); v += __shfl_xor(v, 2); v += __shfl_xor(v, 4); v += __shfl_xor(v, 8);
    float f, rn2; expmap_factor(v, f, rn2);
    fac[r] = f * logmap_factor(rn2);
  }
  __syncthreads();  // all waves done with Kt/Vt reads
  #pragma unroll
  for (int dt = 0; dt < 4; ++dt)
    #pragma unroll
    for (int r = 0; r < 4; ++r) {
      int row = 16 * wid + 4 * g + r;
      *(unsigned short*)(smem + row * 128 + ((2 * (16 * dt + c)) ^ (16 * (row & 7)))) = f2b(oacc[dt][r] * fac[r]);
    }
  __syncthreads();
  {
    int b = bh >> 4, h = bh & 15;
    #pragma unroll
    for (int i = 0; i < 2; ++i) {
      int id = t + 256 * i, row = id >> 3, ch = id & 7;
      uint4 v = *(const uint4*)(smem + row * 128 + ((16 * ch) ^ (16 * (row & 7))));
      *(uint4*)(Om + ((size_t)b * S_LEN + q0 + row) * DM + 64 * h + 8 * ch) = v;
    }
  }
}

extern "C" void kernel_launch(void* const* d_in, const int* in_sizes, int n_in,
                              void* d_out, int out_size, void* d_ws, size_t ws_size,
                              hipStream_t stream) {
  const float* H  = (const float*)d_in[0];
  const float* Wq = (const float*)d_in[1];
  const float* bq = (const float*)d_in[2];
  const float* Wk = (const float*)d_in[3];
  const float* bk = (const float*)d_in[4];
  const float* Wv = (const float*)d_in[5];
  const float* bv = (const float*)d_in[6];
  const float* Wo = (const float*)d_in[7];
  const float* bo = (const float*)d_in[8];

  unsigned char* ws = (unsigned char*)d_ws;
  const size_t MB = 1u << 20;
  unsigned short* Hb  = (unsigned short*)(ws);
  unsigned short* Wqb = (unsigned short*)(ws + 8 * MB);
  unsigned short* Wkb = (unsigned short*)(ws + 10 * MB);
  unsigned short* Wvb = (unsigned short*)(ws + 12 * MB);
  unsigned short* Wob = (unsigned short*)(ws + 14 * MB);
  unsigned short* Qh  = (unsigned short*)(ws + 16 * MB);
  unsigned short* Kh  = (unsigned short*)(ws + 24 * MB);
  unsigned short* Vt  = (unsigned short*)(ws + 32 * MB);
  unsigned short* Omb = (unsigned short*)(ws + 40 * MB);
  float*          q2  = (float*)(ws + 48 * MB);            // 256 KB
  float*          k2  = q2 + (size_t)2 * NH * S_LEN;       // 256 KB -> total 48.5 MiB

  conv_f2b<<<2048, 256, 0, stream>>>(H, (uint4*)Hb);
  conv_w4<<<dim3(512, 4), 256, 0, stream>>>(Wq, Wk, Wv, Wo,
      (uint4*)Wqb, (uint4*)Wkb, (uint4*)Wvb, (uint4*)Wob);
  dim3 gg(32, 16), gb(256);
  gemm_mfma<0><<<gg, gb, 0, stream>>>(Hb, Wqb, bq, Qh);
  gemm_mfma<1><<<gg, gb, 0, stream>>>(Hb, Wkb, bk, Kh);
  gemm_mfma<2><<<gg, gb, 0, stream>>>(Hb, Wvb, bv, Vt);
  row_norms<<<2048, 256, 0, stream>>>(Qh, q2);
  attn_mfma<<<1024, 256, 0, stream>>>(Qh, Kh, Vt, q2, k2, Omb);
  gemm_mfma<3><<<gg, gb, 0, stream>>>(Omb, Wob, bo, d_out);
}